// Round 15
// baseline (338.463 us; speedup 1.0000x reference)
//
#include <hip/hip_runtime.h>

typedef unsigned short u16;
typedef unsigned int u32;
typedef unsigned long long u64;
typedef __attribute__((ext_vector_type(8))) short short8;
typedef __attribute__((ext_vector_type(4))) float f32x4;
typedef __attribute__((ext_vector_type(4))) u32 u32x4;

#define BSHIFT 8               // 256 rows per bucket
#define MAXBUCK 512
#define BCAP 8192              // fixed bucket capacity (mean load 4092, Poisson tail safe)
#define CASTBLK 2048
#define SCATBLK 1024           // R24: 4x finer scatter chunks than R8's failed merge (straggler fix)

__device__ __forceinline__ float bf2f(u32 u) {
    union { u32 i; float f; } v; v.i = u << 16; return v.f;
}
__device__ __forceinline__ float bf2fh(u32 u) {   // high bf16 of a u32: single v_and
    union { u32 i; float f; } v; v.i = u & 0xffff0000u; return v.f;
}
__device__ __forceinline__ u16 f2bf(float f) {
    union { float f; u32 i; } v; v.f = f;
    u32 u = (v.i + 0x7fffu + ((v.i >> 16) & 1u)) >> 16;
    return (u16)u;
}

// 16B-chunk XOR swizzle for LDS fragments (R16): writers spread across 8 bank-quads,
// reads stay conflict-free (measured: SQ_LDS_BANK_CONFLICT 2.8M -> 0).
__device__ __forceinline__ int swz(int ci) { return ci ^ ((ci >> 4) & 7); }

// bijective XCD-chunked swizzle (m204 form)
__device__ __forceinline__ int xcd_swz(int bid, int nbg) {
    int q = nbg >> 3, r = nbg & 7;
    int x = bid & 7, i = bid >> 3;
    return (x < r) ? (x * (q + 1) + i) : (r * (q + 1) + (x - r) * q + i);
}

// ---------------- merged: cast x->bf16 + weight pack + bucket scatter (R24) ----------------
// prep is independent of the CSR chain; merging removes ~35us of sequential stream time.
// R8's merge failed with 256 scatter blocks (6250-edge chunks -> 106us straggler tail);
// 1024 blocks cut the per-block long pole 4x. Cursor atomics ~400k on 391 addresses, pipelined.
__global__ void k_prep_scat(const float4* __restrict__ X, u32* __restrict__ Xb, long total4,
                            const float* __restrict__ Wl1, const float* __restrict__ Wh1,
                            const float* __restrict__ Wm1, const float* __restrict__ Wl2,
                            const float* __restrict__ Wh2, const float* __restrict__ Wm2,
                            u16* __restrict__ Wp1, u16* __restrict__ Wp2,
                            const int* __restrict__ erow, const int* __restrict__ ecol, int e,
                            int nbuck, int* __restrict__ gcursor, u32* __restrict__ bedge) {
    __shared__ int hist[MAXBUCK];
    __shared__ int base[MAXBUCK];
    if (blockIdx.x < CASTBLK) {
        long i = (long)blockIdx.x * blockDim.x + threadIdx.x;
        long stride = (long)CASTBLK * blockDim.x;
        for (; i < total4; i += stride) {
            float4 p = X[i];
            Xb[i * 2 + 0] = (u32)f2bf(p.x) | ((u32)f2bf(p.y) << 16);
            Xb[i * 2 + 1] = (u32)f2bf(p.z) | ((u32)f2bf(p.w) << 16);
        }
        return;
    }
    if (blockIdx.x < CASTBLK + 16) {
        int tid = (blockIdx.x - CASTBLK) * blockDim.x + threadIdx.x;
        int nthr = 16 * blockDim.x;
        for (int m = 0; m < 8; ++m) {
            int layer = m >> 2;          // 0: L1, 1: L2
            int slot = m & 3;            // 0 Wl, 1 -Wh, 2 Wh, 3 Wm
            int Hout = layer ? 64 : 128;
            const float* W = layer ? (slot == 0 ? Wl2 : (slot == 3 ? Wm2 : Wh2))
                                   : (slot == 0 ? Wl1 : (slot == 3 ? Wm1 : Wh1));
            float sgn = (slot == 1) ? -1.f : 1.f;
            u16* dst = (layer ? Wp2 : Wp1) + slot * Hout * 128;
            int total = 128 * Hout;
            for (int i = tid; i < total; i += nthr) {
                int T = i / 2048;
                int c = (i / 512) & 3;
                int lane = (i / 8) & 63;
                int j = i & 7;
                int col = T * 16 + (lane & 15);
                int k = c * 32 + (lane >> 4) * 8 + j;
                dst[i] = f2bf(sgn * W[k * Hout + col]);
            }
        }
        return;
    }
    // ---- bucket scatter: bedge[bk*BCAP + pos] = (col<<8)|(row&255); gcursor ends as counts ----
    int bid = blockIdx.x - (CASTBLK + 16);
    for (int t = threadIdx.x; t < nbuck; t += blockDim.x) hist[t] = 0;
    __syncthreads();
    int chunk = (e + SCATBLK - 1) / SCATBLK;
    int lo = bid * chunk, hi = min(e, lo + chunk);
    for (int i = lo + threadIdx.x; i < hi; i += blockDim.x)
        atomicAdd(&hist[erow[i] >> BSHIFT], 1);
    __syncthreads();
    for (int t = threadIdx.x; t < nbuck; t += blockDim.x) {
        int c = hist[t];
        base[t] = c ? atomicAdd(&gcursor[t], c) : 0;
        hist[t] = 0;
    }
    __syncthreads();
    for (int i = lo + threadIdx.x; i < hi; i += blockDim.x) {
        int r = erow[i];
        int bk = r >> BSHIFT;
        int pos = base[bk] + atomicAdd(&hist[bk], 1);
        if (pos < BCAP)
            bedge[(size_t)bk * BCAP + pos] = ((u32)ecol[i] << 8) | (u32)(r & 255);
    }
}

__global__ void k_bscan2(const int* __restrict__ bcnt, int nbuck, int* __restrict__ boff) {
    __shared__ int lds[MAXBUCK];
    int t = threadIdx.x;
    int v = (t < nbuck) ? bcnt[t] : 0;
    lds[t] = v; __syncthreads();
    for (int off = 1; off < MAXBUCK; off <<= 1) {
        int x = (t >= off) ? lds[t - off] : 0;
        __syncthreads();
        lds[t] += x;
        __syncthreads();
    }
    if (t < nbuck) {
        boff[t] = lds[t] - v;
        if (t == nbuck - 1) boff[nbuck] = lds[t];
    }
}

__global__ void k_bfill2f(const u32* __restrict__ bedge, const int* __restrict__ bcnt,
                          const int* __restrict__ boff, int n,
                          int* __restrict__ row_ptr, float* __restrict__ inv_deg,
                          int* __restrict__ cols) {
    __shared__ int cnt[256];
    __shared__ int incl[256];
    __shared__ int pos[256];
    int b = blockIdx.x, t = threadIdx.x;
    cnt[t] = 0;
    __syncthreads();
    int rbase = b << BSHIFT;
    const u32* src = bedge + (size_t)b * BCAP;
    int cb = bcnt[b];
    int lo = boff[b];
    for (int i = t; i < cb; i += 256)
        atomicAdd(&cnt[src[i] & 255u], 1);
    __syncthreads();
    int v = cnt[t];
    incl[t] = v;
    __syncthreads();
    for (int off = 1; off < 256; off <<= 1) {
        int x = (t >= off) ? incl[t - off] : 0;
        __syncthreads();
        incl[t] += x;
        __syncthreads();
    }
    int excl = incl[t] - v;
    pos[t] = excl;
    int row = rbase + t;
    if (row < n) {
        row_ptr[row] = lo + excl;
        inv_deg[row] = v > 0 ? 1.f / (float)v : 0.f;
    }
    if (b == (int)gridDim.x - 1 && t == 0) row_ptr[n] = lo + cb;
    __syncthreads();
    for (int i = t; i < cb; i += 256) {
        u32 vv = src[i];
        int rl = (int)(vv & 255u);
        int p = lo + atomicAdd(&pos[rl], 1);
        cols[p] = (int)(vv >> 8);
    }
}

// ---------------- fused SpMM + GEMM + attention combine (R23 body, unchanged) ----------------
// Masked full-8 gather batches with a zero dummy row at index n. Non-persistent.
// L1 -> MT=2 (32-row tiles), L2 -> MT=1 (16-row tiles).
template<int HOUT, int MT, bool L1>
__global__ __launch_bounds__(256, 4)
void k_fused(const u32* __restrict__ X2, const int* __restrict__ row_ptr,
             const int* __restrict__ cols, const float* __restrict__ inv_deg,
             const u16* __restrict__ Wp,
             const float* __restrict__ vl, const float* __restrict__ vh, const float* __restrict__ vm,
             const float* __restrict__ att, int n,
             u16* __restrict__ feaOut, float* __restrict__ fOut) {
    constexpr int KPG = HOUT / 64;    // col-tiles per wave: 2 (L1) or 1 (L2)
    constexpr int NTw = 3 * KPG;
    constexpr int ROWS = MT * 16;
    __shared__ __align__(16) u32 AsU[MT * 1024];   // S-fragments (MT x 4c x 256 u32, swizzled)
    __shared__ __align__(16) u32 AxU[MT * 1024];   // X-fragments
    __shared__ int rctr;
    int w = threadIdx.x >> 6, lane = threadIdx.x & 63;
    int ql = lane & 15;
    int ln15 = lane & 15, lq = lane >> 4;
    int tile = xcd_swz(blockIdx.x, gridDim.x);
    int m0 = tile * ROWS;
    const u32x4* X16 = (const u32x4*)X2;   // lane ql covers u32 cols {4ql..4ql+3} = 8 bf16

    if (threadIdx.x == 0) rctr = 0;
    __syncthreads();

    // ---- gather phase: 16 quarters dynamically grab rows 0..ROWS-1 of the tile ----
    for (;;) {
        int rv;
        if (ql == 0) rv = atomicAdd(&rctr, 1);
        rv = __shfl(rv, 0, 16);
        if (rv >= ROWS) break;
        int row = m0 + rv;
        int beg = 0, end = 0;
        float s = 0.f;
        u32x4 px = {0u, 0u, 0u, 0u};
        if (row < n) {
            beg = row_ptr[row];
            end = row_ptr[row + 1];
            s = inv_deg[row];
            px = X16[(size_t)row * 16 + ql];
        }
        float a0 = 0.f, a1 = 0.f, a2 = 0.f, a3 = 0.f, a4 = 0.f, a5 = 0.f, a6 = 0.f, a7 = 0.f;
        int myc = (beg + ql < end) ? cols[beg + ql] : n;
        for (int j0 = beg; j0 < end; j0 += 16) {
            int cnt = end - j0; if (cnt > 16) cnt = 16;
            int nmy = (j0 + 16 + ql < end) ? cols[j0 + 16 + ql] : n;  // prefetch next group
            for (int j = 0; j < cnt; j += 8) {
                // masked full-8 batch: inactive lanes read the zero dummy row n
                int c0 = (j + 0 < cnt) ? __shfl(myc, j + 0, 16) : n;
                int c1 = (j + 1 < cnt) ? __shfl(myc, j + 1, 16) : n;
                int c2 = (j + 2 < cnt) ? __shfl(myc, j + 2, 16) : n;
                int c3 = (j + 3 < cnt) ? __shfl(myc, j + 3, 16) : n;
                int c4 = (j + 4 < cnt) ? __shfl(myc, j + 4, 16) : n;
                int c5 = (j + 5 < cnt) ? __shfl(myc, j + 5, 16) : n;
                int c6 = (j + 6 < cnt) ? __shfl(myc, j + 6, 16) : n;
                int c7 = (j + 7 < cnt) ? __shfl(myc, j + 7, 16) : n;
                u32x4 p0 = X16[(size_t)c0 * 16 + ql];
                u32x4 p1 = X16[(size_t)c1 * 16 + ql];
                u32x4 p2 = X16[(size_t)c2 * 16 + ql];
                u32x4 p3 = X16[(size_t)c3 * 16 + ql];
                u32x4 p4 = X16[(size_t)c4 * 16 + ql];
                u32x4 p5 = X16[(size_t)c5 * 16 + ql];
                u32x4 p6 = X16[(size_t)c6 * 16 + ql];
                u32x4 p7 = X16[(size_t)c7 * 16 + ql];
                a0 += bf2f(p0[0] & 0xffffu) + bf2f(p1[0] & 0xffffu) + bf2f(p2[0] & 0xffffu) + bf2f(p3[0] & 0xffffu)
                    + bf2f(p4[0] & 0xffffu) + bf2f(p5[0] & 0xffffu) + bf2f(p6[0] & 0xffffu) + bf2f(p7[0] & 0xffffu);
                a1 += bf2fh(p0[0]) + bf2fh(p1[0]) + bf2fh(p2[0]) + bf2fh(p3[0])
                    + bf2fh(p4[0]) + bf2fh(p5[0]) + bf2fh(p6[0]) + bf2fh(p7[0]);
                a2 += bf2f(p0[1] & 0xffffu) + bf2f(p1[1] & 0xffffu) + bf2f(p2[1] & 0xffffu) + bf2f(p3[1] & 0xffffu)
                    + bf2f(p4[1] & 0xffffu) + bf2f(p5[1] & 0xffffu) + bf2f(p6[1] & 0xffffu) + bf2f(p7[1] & 0xffffu);
                a3 += bf2fh(p0[1]) + bf2fh(p1[1]) + bf2fh(p2[1]) + bf2fh(p3[1])
                    + bf2fh(p4[1]) + bf2fh(p5[1]) + bf2fh(p6[1]) + bf2fh(p7[1]);
                a4 += bf2f(p0[2] & 0xffffu) + bf2f(p1[2] & 0xffffu) + bf2f(p2[2] & 0xffffu) + bf2f(p3[2] & 0xffffu)
                    + bf2f(p4[2] & 0xffffu) + bf2f(p5[2] & 0xffffu) + bf2f(p6[2] & 0xffffu) + bf2f(p7[2] & 0xffffu);
                a5 += bf2fh(p0[2]) + bf2fh(p1[2]) + bf2fh(p2[2]) + bf2fh(p3[2])
                    + bf2fh(p4[2]) + bf2fh(p5[2]) + bf2fh(p6[2]) + bf2fh(p7[2]);
                a6 += bf2f(p0[3] & 0xffffu) + bf2f(p1[3] & 0xffffu) + bf2f(p2[3] & 0xffffu) + bf2f(p3[3] & 0xffffu)
                    + bf2f(p4[3] & 0xffffu) + bf2f(p5[3] & 0xffffu) + bf2f(p6[3] & 0xffffu) + bf2f(p7[3] & 0xffffu);
                a7 += bf2fh(p0[3]) + bf2fh(p1[3]) + bf2fh(p2[3]) + bf2fh(p3[3])
                    + bf2fh(p4[3]) + bf2fh(p5[3]) + bf2fh(p6[3]) + bf2fh(p7[3]);
            }
            myc = nmy;
        }
        // 16B fragment chunk for local row rv: ci = rt*256 + cc*64 + qq*16 + rr (swizzled)
        int rr = rv & 15, rt = rv >> 4;
        int ci = rt * 256 + (ql >> 2) * 64 + (ql & 3) * 16 + rr;
        int d = swz(ci) * 4;
        u32x4 sv;
        sv[0] = (u32)f2bf(a0 * s) | ((u32)f2bf(a1 * s) << 16);
        sv[1] = (u32)f2bf(a2 * s) | ((u32)f2bf(a3 * s) << 16);
        sv[2] = (u32)f2bf(a4 * s) | ((u32)f2bf(a5 * s) << 16);
        sv[3] = (u32)f2bf(a6 * s) | ((u32)f2bf(a7 * s) << 16);
        *(u32x4*)(AsU + d) = sv;
        *(u32x4*)(AxU + d) = px;
    }

    f32x4 acc[MT][NTw];
#pragma unroll
    for (int mt = 0; mt < MT; ++mt)
#pragma unroll
        for (int k = 0; k < NTw; ++k) { f32x4 z = {0.f, 0.f, 0.f, 0.f}; acc[mt][k] = z; }

    __syncthreads();

    const u16* As = (const u16*)AsU;
    const u16* Ax = (const u16*)AxU;
#pragma unroll
    for (int c = 0; c < 4; ++c) {
#pragma unroll
        for (int kk = 0; kk < KPG; ++kk) {
            int T = w + kk * 4;
            size_t fo = (size_t)(T * 4 + c) * 512 + lane * 8;
            short8 bl  = *(const short8*)(Wp + (size_t)0 * (HOUT * 128) + fo);
            short8 bhn = *(const short8*)(Wp + (size_t)1 * (HOUT * 128) + fo);
            short8 bhp = *(const short8*)(Wp + (size_t)2 * (HOUT * 128) + fo);
            short8 bm  = *(const short8*)(Wp + (size_t)3 * (HOUT * 128) + fo);
#pragma unroll
            for (int mt = 0; mt < MT; ++mt) {
                int ci = (mt * 4 + c) * 64 + lane;
                int o = swz(ci) * 8;
                short8 as = *(const short8*)(As + o);
                short8 ax = *(const short8*)(Ax + o);
                acc[mt][0 * KPG + kk] = __builtin_amdgcn_mfma_f32_16x16x32_bf16(as, bl,  acc[mt][0 * KPG + kk], 0, 0, 0);
                acc[mt][1 * KPG + kk] = __builtin_amdgcn_mfma_f32_16x16x32_bf16(as, bhn, acc[mt][1 * KPG + kk], 0, 0, 0);
                acc[mt][1 * KPG + kk] = __builtin_amdgcn_mfma_f32_16x16x32_bf16(ax, bhp, acc[mt][1 * KPG + kk], 0, 0, 0);
                acc[mt][2 * KPG + kk] = __builtin_amdgcn_mfma_f32_16x16x32_bf16(ax, bm,  acc[mt][2 * KPG + kk], 0, 0, 0);
            }
        }
    }

    float vval[NTw];
#pragma unroll
    for (int k = 0; k < NTw; ++k) {
        int g = k / KPG, kk = k % KPG;
        int col = w * 16 + kk * 64 + ln15;
        vval[k] = (g == 0 ? vl : (g == 1 ? vh : vm))[col];
    }

    __shared__ float part[4][3][ROWS];
    __shared__ float wgt[ROWS][3];
#pragma unroll
    for (int mt = 0; mt < MT; ++mt) {
        float pdg[3][4];
#pragma unroll
        for (int g = 0; g < 3; ++g)
#pragma unroll
            for (int r = 0; r < 4; ++r) pdg[g][r] = 0.f;
#pragma unroll
        for (int k = 0; k < NTw; ++k) {
            int g = k / KPG;
#pragma unroll
            for (int r = 0; r < 4; ++r)
                pdg[g][r] += fmaxf(acc[mt][k][r], 0.f) * vval[k];
        }
#pragma unroll
        for (int off = 1; off < 16; off <<= 1)
#pragma unroll
            for (int g = 0; g < 3; ++g)
#pragma unroll
                for (int r = 0; r < 4; ++r)
                    pdg[g][r] += __shfl_xor(pdg[g][r], off);
        if (ln15 == 0) {
            int rbase = mt * 16 + lq * 4;
#pragma unroll
            for (int g = 0; g < 3; ++g)
#pragma unroll
                for (int r = 0; r < 4; ++r)
                    part[w][g][rbase + r] = pdg[g][r];
        }
    }
    __syncthreads();
    if (threadIdx.x < ROWS) {
        int row = threadIdx.x;
        float d0 = 0.f, d1 = 0.f, d2 = 0.f;
#pragma unroll
        for (int q = 0; q < 4; ++q) {
            d0 += part[q][0][row];
            d1 += part[q][1][row];
            d2 += part[q][2][row];
        }
        float s0 = 1.f / (1.f + __expf(-d0));
        float s1 = 1.f / (1.f + __expf(-d1));
        float s2 = 1.f / (1.f + __expf(-d2));
        float a0 = (s0 * att[0] + s1 * att[3] + s2 * att[6]) * (1.f / 3.f);
        float a1 = (s0 * att[1] + s1 * att[4] + s2 * att[7]) * (1.f / 3.f);
        float a2 = (s0 * att[2] + s1 * att[5] + s2 * att[8]) * (1.f / 3.f);
        float mx = fmaxf(a0, fmaxf(a1, a2));
        float e0 = __expf(a0 - mx), e1 = __expf(a1 - mx), e2 = __expf(a2 - mx);
        float inv = 3.f / (e0 + e1 + e2);
        wgt[row][0] = e0 * inv;
        wgt[row][1] = e1 * inv;
        wgt[row][2] = e2 * inv;
    }
    __syncthreads();

#pragma unroll
    for (int mt = 0; mt < MT; ++mt)
#pragma unroll
        for (int kk = 0; kk < KPG; ++kk)
#pragma unroll
            for (int r = 0; r < 4; ++r) {
                int row_local = mt * 16 + lq * 4 + r;
                int row = m0 + row_local;
                if (row < n) {
                    int col = w * 16 + kk * 64 + ln15;
                    float w0 = wgt[row_local][0], w1 = wgt[row_local][1], w2 = wgt[row_local][2];
                    float ol = fmaxf(acc[mt][0 * KPG + kk][r], 0.f);
                    float oh = fmaxf(acc[mt][1 * KPG + kk][r], 0.f);
                    float om = fmaxf(acc[mt][2 * KPG + kk][r], 0.f);
                    float val = w0 * ol + w1 * oh + w2 * om;
                    if (L1)
                        feaOut[(size_t)row * HOUT + col] = f2bf(fmaxf(val, 0.f));
                    else
                        fOut[(size_t)row * HOUT + col] = val;
                }
            }
}

extern "C" void kernel_launch(void* const* d_in, const int* in_sizes, int n_in,
                              void* d_out, int out_size, void* d_ws, size_t ws_size,
                              hipStream_t stream) {
    const int F = 128;
    int n = in_sizes[0] / F;
    int e = in_sizes[1] / 2;
    int nbuck = (n + (1 << BSHIFT) - 1) >> BSHIFT;
    const float* x = (const float*)d_in[0];
    const int* ei = (const int*)d_in[1];
    const int* erow = ei;
    const int* ecol = ei + e;
    const float *Wl1 = (const float*)d_in[2], *Wh1 = (const float*)d_in[3], *Wm1 = (const float*)d_in[4];
    const float *vl1 = (const float*)d_in[5], *vh1 = (const float*)d_in[6], *vm1 = (const float*)d_in[7];
    const float* att1 = (const float*)d_in[8];
    const float *Wl2 = (const float*)d_in[9], *Wh2 = (const float*)d_in[10], *Wm2 = (const float*)d_in[11];
    const float *vl2 = (const float*)d_in[12], *vh2 = (const float*)d_in[13], *vm2 = (const float*)d_in[14];
    const float* att2 = (const float*)d_in[15];
    float* out = (float*)d_out;

    char* ws = (char*)d_ws;
    size_t off = 0;
    auto alloc = [&](size_t b) -> void* {
        void* p = ws + off;
        off = (off + b + 255) & ~(size_t)255;
        return p;
    };
    int* row_ptr = (int*)alloc((size_t)(n + 1) * 4);
    float* inv_deg = (float*)alloc((size_t)n * 4);
    int* gcursor = (int*)alloc(MAXBUCK * 4);
    int* boff = (int*)alloc((MAXBUCK + 1) * 4);
    u32* bedge = (u32*)alloc((size_t)MAXBUCK * BCAP * 4);
    int* cols = (int*)alloc((size_t)e * 4);
    u16* Xb = (u16*)alloc((size_t)(n + 1) * 128 * 2);   // +1 zero dummy row (gather mask target)
    u16* fea = (u16*)alloc((size_t)(n + 1) * 128 * 2);  // +1 zero dummy row
    u16* Wp1 = (u16*)alloc((size_t)4 * 128 * 128 * 2);
    u16* Wp2 = (u16*)alloc((size_t)4 * 64 * 128 * 2);
    (void)ws_size; (void)n_in; (void)out_size;

    hipMemsetAsync(gcursor, 0, (size_t)MAXBUCK * 4, stream);
    hipMemsetAsync(Xb + (size_t)n * 128, 0, 256, stream);   // zero dummy row
    hipMemsetAsync(fea + (size_t)n * 128, 0, 256, stream);  // zero dummy row

    k_prep_scat<<<CASTBLK + 16 + SCATBLK, 256, 0, stream>>>(
        (const float4*)x, (u32*)Xb, (long)n * 32,
        Wl1, Wh1, Wm1, Wl2, Wh2, Wm2, Wp1, Wp2,
        erow, ecol, e, nbuck, gcursor, bedge);
    k_bscan2<<<1, MAXBUCK, 0, stream>>>(gcursor, nbuck, boff);
    k_bfill2f<<<nbuck, 256, 0, stream>>>(bedge, gcursor, boff, n, row_ptr, inv_deg, cols);

    int gb1 = (n + 31) / 32;
    int gb2 = (n + 15) / 16;

    // layer 1 (fused spmm+gemm, 32-row tiles)
    k_fused<128, 2, true><<<gb1, 256, 0, stream>>>((const u32*)Xb, row_ptr, cols, inv_deg,
                                                   Wp1, vl1, vh1, vm1, att1, n, fea, nullptr);
    // layer 2 (16-row tiles)
    k_fused<64, 1, false><<<gb2, 256, 0, stream>>>((const u32*)fea, row_ptr, cols, inv_deg,
                                                   Wp2, vl2, vh2, vm2, att2, n, nullptr, out);
}

// Round 16
// 332.628 us; speedup vs baseline: 1.0175x; 1.0175x over previous
//
#include <hip/hip_runtime.h>

typedef unsigned short u16;
typedef unsigned int u32;
typedef unsigned long long u64;
typedef __attribute__((ext_vector_type(8))) short short8;
typedef __attribute__((ext_vector_type(4))) float f32x4;
typedef __attribute__((ext_vector_type(4))) u32 u32x4;

#define BSHIFT 8               // 256 rows per bucket
#define MAXBUCK 512
#define BCAP 8192              // fixed bucket capacity (mean load 4092, Poisson tail safe)
#define CASTBLK 2048
#define SCATBLK 1024

__device__ __forceinline__ float bf2f(u32 u) {
    union { u32 i; float f; } v; v.i = u << 16; return v.f;
}
__device__ __forceinline__ float bf2fh(u32 u) {   // high bf16 of a u32: single v_and
    union { u32 i; float f; } v; v.i = u & 0xffff0000u; return v.f;
}
__device__ __forceinline__ u16 f2bf(float f) {
    union { float f; u32 i; } v; v.f = f;
    u32 u = (v.i + 0x7fffu + ((v.i >> 16) & 1u)) >> 16;
    return (u16)u;
}

// 16B-chunk XOR swizzle for LDS fragments (R16): writers spread across 8 bank-quads,
// reads stay conflict-free (measured: SQ_LDS_BANK_CONFLICT 2.8M -> 0).
__device__ __forceinline__ int swz(int ci) { return ci ^ ((ci >> 4) & 7); }

// bijective XCD-chunked swizzle (m204 form)
__device__ __forceinline__ int xcd_swz(int bid, int nbg) {
    int q = nbg >> 3, r = nbg & 7;
    int x = bid & 7, i = bid >> 3;
    return (x < r) ? (x * (q + 1) + i) : (r * (q + 1) + (x - r) * q + i);
}

// ---------------- merged: bucket scatter + cast x->bf16 + weight pack (R25) ----------------
// R14 post-mortem: merged-with-scatter-LAST never overlapped — blocks dispatch in ascending
// order, so the 2064 cast blocks ran first and the latency-bound scatter executed as a
// near-solo tail (R11 merged counters: occupancy 14%). R25 puts SCATTER FIRST: its
// latency tail now hides under the BW-bound cast -> dispatch ~ max(cast, scatter).
__global__ void k_prep_scat(const float4* __restrict__ X, u32* __restrict__ Xb, long total4,
                            const float* __restrict__ Wl1, const float* __restrict__ Wh1,
                            const float* __restrict__ Wm1, const float* __restrict__ Wl2,
                            const float* __restrict__ Wh2, const float* __restrict__ Wm2,
                            u16* __restrict__ Wp1, u16* __restrict__ Wp2,
                            const int* __restrict__ erow, const int* __restrict__ ecol, int e,
                            int nbuck, int* __restrict__ gcursor, u32* __restrict__ bedge) {
    __shared__ int hist[MAXBUCK];
    __shared__ int base[MAXBUCK];
    if (blockIdx.x < SCATBLK) {
        // ---- bucket scatter: bedge[bk*BCAP + pos] = (col<<8)|(row&255); gcursor -> counts ----
        int bid = blockIdx.x;
        for (int t = threadIdx.x; t < nbuck; t += blockDim.x) hist[t] = 0;
        __syncthreads();
        int chunk = (e + SCATBLK - 1) / SCATBLK;
        int lo = bid * chunk, hi = min(e, lo + chunk);
        for (int i = lo + threadIdx.x; i < hi; i += blockDim.x)
            atomicAdd(&hist[erow[i] >> BSHIFT], 1);
        __syncthreads();
        for (int t = threadIdx.x; t < nbuck; t += blockDim.x) {
            int c = hist[t];
            base[t] = c ? atomicAdd(&gcursor[t], c) : 0;
            hist[t] = 0;
        }
        __syncthreads();
        for (int i = lo + threadIdx.x; i < hi; i += blockDim.x) {
            int r = erow[i];
            int bk = r >> BSHIFT;
            int pos = base[bk] + atomicAdd(&hist[bk], 1);
            if (pos < BCAP)
                bedge[(size_t)bk * BCAP + pos] = ((u32)ecol[i] << 8) | (u32)(r & 255);
        }
        return;
    }
    if (blockIdx.x < SCATBLK + CASTBLK) {
        long i = (long)(blockIdx.x - SCATBLK) * blockDim.x + threadIdx.x;
        long stride = (long)CASTBLK * blockDim.x;
        for (; i < total4; i += stride) {
            float4 p = X[i];
            Xb[i * 2 + 0] = (u32)f2bf(p.x) | ((u32)f2bf(p.y) << 16);
            Xb[i * 2 + 1] = (u32)f2bf(p.z) | ((u32)f2bf(p.w) << 16);
        }
        return;
    }
    int tid = (blockIdx.x - (SCATBLK + CASTBLK)) * blockDim.x + threadIdx.x;
    int nthr = 16 * blockDim.x;
    for (int m = 0; m < 8; ++m) {
        int layer = m >> 2;          // 0: L1, 1: L2
        int slot = m & 3;            // 0 Wl, 1 -Wh, 2 Wh, 3 Wm
        int Hout = layer ? 64 : 128;
        const float* W = layer ? (slot == 0 ? Wl2 : (slot == 3 ? Wm2 : Wh2))
                               : (slot == 0 ? Wl1 : (slot == 3 ? Wm1 : Wh1));
        float sgn = (slot == 1) ? -1.f : 1.f;
        u16* dst = (layer ? Wp2 : Wp1) + slot * Hout * 128;
        int total = 128 * Hout;
        for (int i = tid; i < total; i += nthr) {
            int T = i / 2048;
            int c = (i / 512) & 3;
            int lane = (i / 8) & 63;
            int j = i & 7;
            int col = T * 16 + (lane & 15);
            int k = c * 32 + (lane >> 4) * 8 + j;
            dst[i] = f2bf(sgn * W[k * Hout + col]);
        }
    }
}

// ---------------- per-bucket CSR fill with INLINE prefix scan (R25: k_bscan2 folded in;
// each block computes lo = sum(bcnt[0..b-1]) via strided partial sums + 256-wide reduce) ----
__global__ void k_bfill3(const u32* __restrict__ bedge, const int* __restrict__ bcnt,
                         int n, int nbuck,
                         int* __restrict__ row_ptr, float* __restrict__ inv_deg,
                         int* __restrict__ cols) {
    __shared__ int cnt[256];
    __shared__ int incl[256];
    __shared__ int pos[256];
    __shared__ int lobase;
    int b = blockIdx.x, t = threadIdx.x;
    // inline exclusive prefix of bucket counts
    {
        int s = 0;
        for (int i = t; i < b; i += 256) s += bcnt[i];
        cnt[t] = s;
        __syncthreads();
        for (int off = 128; off > 0; off >>= 1) {
            if (t < off) cnt[t] += cnt[t + off];
            __syncthreads();
        }
        if (t == 0) lobase = cnt[0];
        __syncthreads();
    }
    int lo = lobase;
    int cb = bcnt[b];
    cnt[t] = 0;
    __syncthreads();
    int rbase = b << BSHIFT;
    const u32* src = bedge + (size_t)b * BCAP;
    for (int i = t; i < cb; i += 256)
        atomicAdd(&cnt[src[i] & 255u], 1);
    __syncthreads();
    int v = cnt[t];
    incl[t] = v;
    __syncthreads();
    for (int off = 1; off < 256; off <<= 1) {
        int x = (t >= off) ? incl[t - off] : 0;
        __syncthreads();
        incl[t] += x;
        __syncthreads();
    }
    int excl = incl[t] - v;
    pos[t] = excl;
    int row = rbase + t;
    if (row < n) {
        row_ptr[row] = lo + excl;
        inv_deg[row] = v > 0 ? 1.f / (float)v : 0.f;
    }
    if (b == nbuck - 1 && t == 0) row_ptr[n] = lo + cb;
    __syncthreads();
    for (int i = t; i < cb; i += 256) {
        u32 vv = src[i];
        int rl = (int)(vv & 255u);
        int p = lo + atomicAdd(&pos[rl], 1);
        cols[p] = (int)(vv >> 8);
    }
}

// ---------------- fused SpMM + GEMM + attention combine (R23 body, unchanged) ----------------
// Masked full-8 gather batches with a zero dummy row at index n. Non-persistent.
// L1 -> MT=2 (32-row tiles), L2 -> MT=1 (16-row tiles).
template<int HOUT, int MT, bool L1>
__global__ __launch_bounds__(256, 4)
void k_fused(const u32* __restrict__ X2, const int* __restrict__ row_ptr,
             const int* __restrict__ cols, const float* __restrict__ inv_deg,
             const u16* __restrict__ Wp,
             const float* __restrict__ vl, const float* __restrict__ vh, const float* __restrict__ vm,
             const float* __restrict__ att, int n,
             u16* __restrict__ feaOut, float* __restrict__ fOut) {
    constexpr int KPG = HOUT / 64;    // col-tiles per wave: 2 (L1) or 1 (L2)
    constexpr int NTw = 3 * KPG;
    constexpr int ROWS = MT * 16;
    __shared__ __align__(16) u32 AsU[MT * 1024];   // S-fragments (MT x 4c x 256 u32, swizzled)
    __shared__ __align__(16) u32 AxU[MT * 1024];   // X-fragments
    __shared__ int rctr;
    int w = threadIdx.x >> 6, lane = threadIdx.x & 63;
    int ql = lane & 15;
    int ln15 = lane & 15, lq = lane >> 4;
    int tile = xcd_swz(blockIdx.x, gridDim.x);
    int m0 = tile * ROWS;
    const u32x4* X16 = (const u32x4*)X2;   // lane ql covers u32 cols {4ql..4ql+3} = 8 bf16

    if (threadIdx.x == 0) rctr = 0;
    __syncthreads();

    // ---- gather phase: 16 quarters dynamically grab rows 0..ROWS-1 of the tile ----
    for (;;) {
        int rv;
        if (ql == 0) rv = atomicAdd(&rctr, 1);
        rv = __shfl(rv, 0, 16);
        if (rv >= ROWS) break;
        int row = m0 + rv;
        int beg = 0, end = 0;
        float s = 0.f;
        u32x4 px = {0u, 0u, 0u, 0u};
        if (row < n) {
            beg = row_ptr[row];
            end = row_ptr[row + 1];
            s = inv_deg[row];
            px = X16[(size_t)row * 16 + ql];
        }
        float a0 = 0.f, a1 = 0.f, a2 = 0.f, a3 = 0.f, a4 = 0.f, a5 = 0.f, a6 = 0.f, a7 = 0.f;
        int myc = (beg + ql < end) ? cols[beg + ql] : n;
        for (int j0 = beg; j0 < end; j0 += 16) {
            int cnt = end - j0; if (cnt > 16) cnt = 16;
            int nmy = (j0 + 16 + ql < end) ? cols[j0 + 16 + ql] : n;  // prefetch next group
            for (int j = 0; j < cnt; j += 8) {
                // masked full-8 batch: inactive lanes read the zero dummy row n
                int c0 = (j + 0 < cnt) ? __shfl(myc, j + 0, 16) : n;
                int c1 = (j + 1 < cnt) ? __shfl(myc, j + 1, 16) : n;
                int c2 = (j + 2 < cnt) ? __shfl(myc, j + 2, 16) : n;
                int c3 = (j + 3 < cnt) ? __shfl(myc, j + 3, 16) : n;
                int c4 = (j + 4 < cnt) ? __shfl(myc, j + 4, 16) : n;
                int c5 = (j + 5 < cnt) ? __shfl(myc, j + 5, 16) : n;
                int c6 = (j + 6 < cnt) ? __shfl(myc, j + 6, 16) : n;
                int c7 = (j + 7 < cnt) ? __shfl(myc, j + 7, 16) : n;
                u32x4 p0 = X16[(size_t)c0 * 16 + ql];
                u32x4 p1 = X16[(size_t)c1 * 16 + ql];
                u32x4 p2 = X16[(size_t)c2 * 16 + ql];
                u32x4 p3 = X16[(size_t)c3 * 16 + ql];
                u32x4 p4 = X16[(size_t)c4 * 16 + ql];
                u32x4 p5 = X16[(size_t)c5 * 16 + ql];
                u32x4 p6 = X16[(size_t)c6 * 16 + ql];
                u32x4 p7 = X16[(size_t)c7 * 16 + ql];
                a0 += bf2f(p0[0] & 0xffffu) + bf2f(p1[0] & 0xffffu) + bf2f(p2[0] & 0xffffu) + bf2f(p3[0] & 0xffffu)
                    + bf2f(p4[0] & 0xffffu) + bf2f(p5[0] & 0xffffu) + bf2f(p6[0] & 0xffffu) + bf2f(p7[0] & 0xffffu);
                a1 += bf2fh(p0[0]) + bf2fh(p1[0]) + bf2fh(p2[0]) + bf2fh(p3[0])
                    + bf2fh(p4[0]) + bf2fh(p5[0]) + bf2fh(p6[0]) + bf2fh(p7[0]);
                a2 += bf2f(p0[1] & 0xffffu) + bf2f(p1[1] & 0xffffu) + bf2f(p2[1] & 0xffffu) + bf2f(p3[1] & 0xffffu)
                    + bf2f(p4[1] & 0xffffu) + bf2f(p5[1] & 0xffffu) + bf2f(p6[1] & 0xffffu) + bf2f(p7[1] & 0xffffu);
                a3 += bf2fh(p0[1]) + bf2fh(p1[1]) + bf2fh(p2[1]) + bf2fh(p3[1])
                    + bf2fh(p4[1]) + bf2fh(p5[1]) + bf2fh(p6[1]) + bf2fh(p7[1]);
                a4 += bf2f(p0[2] & 0xffffu) + bf2f(p1[2] & 0xffffu) + bf2f(p2[2] & 0xffffu) + bf2f(p3[2] & 0xffffu)
                    + bf2f(p4[2] & 0xffffu) + bf2f(p5[2] & 0xffffu) + bf2f(p6[2] & 0xffffu) + bf2f(p7[2] & 0xffffu);
                a5 += bf2fh(p0[2]) + bf2fh(p1[2]) + bf2fh(p2[2]) + bf2fh(p3[2])
                    + bf2fh(p4[2]) + bf2fh(p5[2]) + bf2fh(p6[2]) + bf2fh(p7[2]);
                a6 += bf2f(p0[3] & 0xffffu) + bf2f(p1[3] & 0xffffu) + bf2f(p2[3] & 0xffffu) + bf2f(p3[3] & 0xffffu)
                    + bf2f(p4[3] & 0xffffu) + bf2f(p5[3] & 0xffffu) + bf2f(p6[3] & 0xffffu) + bf2f(p7[3] & 0xffffu);
                a7 += bf2fh(p0[3]) + bf2fh(p1[3]) + bf2fh(p2[3]) + bf2fh(p3[3])
                    + bf2fh(p4[3]) + bf2fh(p5[3]) + bf2fh(p6[3]) + bf2fh(p7[3]);
            }
            myc = nmy;
        }
        // 16B fragment chunk for local row rv: ci = rt*256 + cc*64 + qq*16 + rr (swizzled)
        int rr = rv & 15, rt = rv >> 4;
        int ci = rt * 256 + (ql >> 2) * 64 + (ql & 3) * 16 + rr;
        int d = swz(ci) * 4;
        u32x4 sv;
        sv[0] = (u32)f2bf(a0 * s) | ((u32)f2bf(a1 * s) << 16);
        sv[1] = (u32)f2bf(a2 * s) | ((u32)f2bf(a3 * s) << 16);
        sv[2] = (u32)f2bf(a4 * s) | ((u32)f2bf(a5 * s) << 16);
        sv[3] = (u32)f2bf(a6 * s) | ((u32)f2bf(a7 * s) << 16);
        *(u32x4*)(AsU + d) = sv;
        *(u32x4*)(AxU + d) = px;
    }

    f32x4 acc[MT][NTw];
#pragma unroll
    for (int mt = 0; mt < MT; ++mt)
#pragma unroll
        for (int k = 0; k < NTw; ++k) { f32x4 z = {0.f, 0.f, 0.f, 0.f}; acc[mt][k] = z; }

    __syncthreads();

    const u16* As = (const u16*)AsU;
    const u16* Ax = (const u16*)AxU;
#pragma unroll
    for (int c = 0; c < 4; ++c) {
#pragma unroll
        for (int kk = 0; kk < KPG; ++kk) {
            int T = w + kk * 4;
            size_t fo = (size_t)(T * 4 + c) * 512 + lane * 8;
            short8 bl  = *(const short8*)(Wp + (size_t)0 * (HOUT * 128) + fo);
            short8 bhn = *(const short8*)(Wp + (size_t)1 * (HOUT * 128) + fo);
            short8 bhp = *(const short8*)(Wp + (size_t)2 * (HOUT * 128) + fo);
            short8 bm  = *(const short8*)(Wp + (size_t)3 * (HOUT * 128) + fo);
#pragma unroll
            for (int mt = 0; mt < MT; ++mt) {
                int ci = (mt * 4 + c) * 64 + lane;
                int o = swz(ci) * 8;
                short8 as = *(const short8*)(As + o);
                short8 ax = *(const short8*)(Ax + o);
                acc[mt][0 * KPG + kk] = __builtin_amdgcn_mfma_f32_16x16x32_bf16(as, bl,  acc[mt][0 * KPG + kk], 0, 0, 0);
                acc[mt][1 * KPG + kk] = __builtin_amdgcn_mfma_f32_16x16x32_bf16(as, bhn, acc[mt][1 * KPG + kk], 0, 0, 0);
                acc[mt][1 * KPG + kk] = __builtin_amdgcn_mfma_f32_16x16x32_bf16(ax, bhp, acc[mt][1 * KPG + kk], 0, 0, 0);
                acc[mt][2 * KPG + kk] = __builtin_amdgcn_mfma_f32_16x16x32_bf16(ax, bm,  acc[mt][2 * KPG + kk], 0, 0, 0);
            }
        }
    }

    float vval[NTw];
#pragma unroll
    for (int k = 0; k < NTw; ++k) {
        int g = k / KPG, kk = k % KPG;
        int col = w * 16 + kk * 64 + ln15;
        vval[k] = (g == 0 ? vl : (g == 1 ? vh : vm))[col];
    }

    __shared__ float part[4][3][ROWS];
    __shared__ float wgt[ROWS][3];
#pragma unroll
    for (int mt = 0; mt < MT; ++mt) {
        float pdg[3][4];
#pragma unroll
        for (int g = 0; g < 3; ++g)
#pragma unroll
            for (int r = 0; r < 4; ++r) pdg[g][r] = 0.f;
#pragma unroll
        for (int k = 0; k < NTw; ++k) {
            int g = k / KPG;
#pragma unroll
            for (int r = 0; r < 4; ++r)
                pdg[g][r] += fmaxf(acc[mt][k][r], 0.f) * vval[k];
        }
#pragma unroll
        for (int off = 1; off < 16; off <<= 1)
#pragma unroll
            for (int g = 0; g < 3; ++g)
#pragma unroll
                for (int r = 0; r < 4; ++r)
                    pdg[g][r] += __shfl_xor(pdg[g][r], off);
        if (ln15 == 0) {
            int rbase = mt * 16 + lq * 4;
#pragma unroll
            for (int g = 0; g < 3; ++g)
#pragma unroll
                for (int r = 0; r < 4; ++r)
                    part[w][g][rbase + r] = pdg[g][r];
        }
    }
    __syncthreads();
    if (threadIdx.x < ROWS) {
        int row = threadIdx.x;
        float d0 = 0.f, d1 = 0.f, d2 = 0.f;
#pragma unroll
        for (int q = 0; q < 4; ++q) {
            d0 += part[q][0][row];
            d1 += part[q][1][row];
            d2 += part[q][2][row];
        }
        float s0 = 1.f / (1.f + __expf(-d0));
        float s1 = 1.f / (1.f + __expf(-d1));
        float s2 = 1.f / (1.f + __expf(-d2));
        float a0 = (s0 * att[0] + s1 * att[3] + s2 * att[6]) * (1.f / 3.f);
        float a1 = (s0 * att[1] + s1 * att[4] + s2 * att[7]) * (1.f / 3.f);
        float a2 = (s0 * att[2] + s1 * att[5] + s2 * att[8]) * (1.f / 3.f);
        float mx = fmaxf(a0, fmaxf(a1, a2));
        float e0 = __expf(a0 - mx), e1 = __expf(a1 - mx), e2 = __expf(a2 - mx);
        float inv = 3.f / (e0 + e1 + e2);
        wgt[row][0] = e0 * inv;
        wgt[row][1] = e1 * inv;
        wgt[row][2] = e2 * inv;
    }
    __syncthreads();

#pragma unroll
    for (int mt = 0; mt < MT; ++mt)
#pragma unroll
        for (int kk = 0; kk < KPG; ++kk)
#pragma unroll
            for (int r = 0; r < 4; ++r) {
                int row_local = mt * 16 + lq * 4 + r;
                int row = m0 + row_local;
                if (row < n) {
                    int col = w * 16 + kk * 64 + ln15;
                    float w0 = wgt[row_local][0], w1 = wgt[row_local][1], w2 = wgt[row_local][2];
                    float ol = fmaxf(acc[mt][0 * KPG + kk][r], 0.f);
                    float oh = fmaxf(acc[mt][1 * KPG + kk][r], 0.f);
                    float om = fmaxf(acc[mt][2 * KPG + kk][r], 0.f);
                    float val = w0 * ol + w1 * oh + w2 * om;
                    if (L1)
                        feaOut[(size_t)row * HOUT + col] = f2bf(fmaxf(val, 0.f));
                    else
                        fOut[(size_t)row * HOUT + col] = val;
                }
            }
}

extern "C" void kernel_launch(void* const* d_in, const int* in_sizes, int n_in,
                              void* d_out, int out_size, void* d_ws, size_t ws_size,
                              hipStream_t stream) {
    const int F = 128;
    int n = in_sizes[0] / F;
    int e = in_sizes[1] / 2;
    int nbuck = (n + (1 << BSHIFT) - 1) >> BSHIFT;
    const float* x = (const float*)d_in[0];
    const int* ei = (const int*)d_in[1];
    const int* erow = ei;
    const int* ecol = ei + e;
    const float *Wl1 = (const float*)d_in[2], *Wh1 = (const float*)d_in[3], *Wm1 = (const float*)d_in[4];
    const float *vl1 = (const float*)d_in[5], *vh1 = (const float*)d_in[6], *vm1 = (const float*)d_in[7];
    const float* att1 = (const float*)d_in[8];
    const float *Wl2 = (const float*)d_in[9], *Wh2 = (const float*)d_in[10], *Wm2 = (const float*)d_in[11];
    const float *vl2 = (const float*)d_in[12], *vh2 = (const float*)d_in[13], *vm2 = (const float*)d_in[14];
    const float* att2 = (const float*)d_in[15];
    float* out = (float*)d_out;

    char* ws = (char*)d_ws;
    size_t off = 0;
    auto alloc = [&](size_t b) -> void* {
        void* p = ws + off;
        off = (off + b + 255) & ~(size_t)255;
        return p;
    };
    int* row_ptr = (int*)alloc((size_t)(n + 1) * 4);
    float* inv_deg = (float*)alloc((size_t)n * 4);
    int* gcursor = (int*)alloc(MAXBUCK * 4);
    u32* bedge = (u32*)alloc((size_t)MAXBUCK * BCAP * 4);
    int* cols = (int*)alloc((size_t)e * 4);
    u16* Xb = (u16*)alloc((size_t)(n + 1) * 128 * 2);   // +1 zero dummy row (gather mask target)
    u16* fea = (u16*)alloc((size_t)(n + 1) * 128 * 2);  // +1 zero dummy row
    u16* Wp1 = (u16*)alloc((size_t)4 * 128 * 128 * 2);
    u16* Wp2 = (u16*)alloc((size_t)4 * 64 * 128 * 2);
    (void)ws_size; (void)n_in; (void)out_size;

    hipMemsetAsync(gcursor, 0, (size_t)MAXBUCK * 4, stream);
    hipMemsetAsync(Xb + (size_t)n * 128, 0, 256, stream);   // zero dummy row
    hipMemsetAsync(fea + (size_t)n * 128, 0, 256, stream);  // zero dummy row

    k_prep_scat<<<SCATBLK + CASTBLK + 16, 256, 0, stream>>>(
        (const float4*)x, (u32*)Xb, (long)n * 32,
        Wl1, Wh1, Wm1, Wl2, Wh2, Wm2, Wp1, Wp2,
        erow, ecol, e, nbuck, gcursor, bedge);
    k_bfill3<<<nbuck, 256, 0, stream>>>(bedge, gcursor, n, nbuck, row_ptr, inv_deg, cols);

    int gb1 = (n + 31) / 32;
    int gb2 = (n + 15) / 16;

    // layer 1 (fused spmm+gemm, 32-row tiles)
    k_fused<128, 2, true><<<gb1, 256, 0, stream>>>((const u32*)Xb, row_ptr, cols, inv_deg,
                                                   Wp1, vl1, vh1, vm1, att1, n, fea, nullptr);
    // layer 2 (16-row tiles)
    k_fused<64, 1, false><<<gb2, 256, 0, stream>>>((const u32*)fea, row_ptr, cols, inv_deg,
                                                   Wp2, vl2, vh2, vm2, att2, n, nullptr, out);
}

// Round 17
// 325.809 us; speedup vs baseline: 1.0388x; 1.0209x over previous
//
#include <hip/hip_runtime.h>

typedef unsigned short u16;
typedef unsigned int u32;
typedef unsigned long long u64;
typedef __attribute__((ext_vector_type(8))) short short8;
typedef __attribute__((ext_vector_type(4))) float f32x4;
typedef __attribute__((ext_vector_type(4))) u32 u32x4;

#define BSHIFT 8               // 256 rows per bucket
#define MAXBUCK 512
#define BCAP 8192              // fixed bucket capacity (mean load 4092, Poisson tail safe)
#define CASTBLK 2048
#define SCATBLK 512

__device__ __forceinline__ float bf2f(u32 u) {
    union { u32 i; float f; } v; v.i = u << 16; return v.f;
}
__device__ __forceinline__ float bf2fh(u32 u) {   // high bf16 of a u32: single v_and
    union { u32 i; float f; } v; v.i = u & 0xffff0000u; return v.f;
}
__device__ __forceinline__ u16 f2bf(float f) {
    union { float f; u32 i; } v; v.f = f;
    u32 u = (v.i + 0x7fffu + ((v.i >> 16) & 1u)) >> 16;
    return (u16)u;
}

// 16B-chunk XOR swizzle for LDS fragments (R16): writers spread across 8 bank-quads,
// reads stay conflict-free (measured: SQ_LDS_BANK_CONFLICT 2.8M -> 0).
__device__ __forceinline__ int swz(int ci) { return ci ^ ((ci >> 4) & 7); }

// bijective XCD-chunked swizzle (m204 form)
__device__ __forceinline__ int xcd_swz(int bid, int nbg) {
    int q = nbg >> 3, r = nbg & 7;
    int x = bid & 7, i = bid >> 3;
    return (x < r) ? (x * (q + 1) + i) : (r * (q + 1) + (x - r) * q + i);
}

// ---------------- cast x -> bf16 + weight pack + dummy-row zeroing (R26) ----------------
// R13's split form (measured best front-end). The weight-pack branch also zeroes the two
// dummy rows (Xb[n], fea[n]) -> removes 2 small memset dispatches; safe since dummies are
// only read by the fused kernels which run strictly after this dispatch.
__global__ void k_prep(const float4* __restrict__ X, u32* __restrict__ Xb, long total4,
                       const float* __restrict__ Wl1, const float* __restrict__ Wh1,
                       const float* __restrict__ Wm1, const float* __restrict__ Wl2,
                       const float* __restrict__ Wh2, const float* __restrict__ Wm2,
                       u16* __restrict__ Wp1, u16* __restrict__ Wp2,
                       u32* __restrict__ XbDum, u32* __restrict__ feaDum) {
    if (blockIdx.x < CASTBLK) {
        long i = (long)blockIdx.x * blockDim.x + threadIdx.x;
        long stride = (long)CASTBLK * blockDim.x;
        for (; i < total4; i += stride) {
            float4 p = X[i];
            Xb[i * 2 + 0] = (u32)f2bf(p.x) | ((u32)f2bf(p.y) << 16);
            Xb[i * 2 + 1] = (u32)f2bf(p.z) | ((u32)f2bf(p.w) << 16);
        }
        return;
    }
    if (blockIdx.x == CASTBLK && threadIdx.x < 128) {
        // zero dummy rows (64 u32 each)
        if (threadIdx.x < 64) XbDum[threadIdx.x] = 0u;
        else feaDum[threadIdx.x - 64] = 0u;
    }
    int tid = (blockIdx.x - CASTBLK) * blockDim.x + threadIdx.x;
    int nthr = 16 * blockDim.x;
    for (int m = 0; m < 8; ++m) {
        int layer = m >> 2;          // 0: L1, 1: L2
        int slot = m & 3;            // 0 Wl, 1 -Wh, 2 Wh, 3 Wm
        int Hout = layer ? 64 : 128;
        const float* W = layer ? (slot == 0 ? Wl2 : (slot == 3 ? Wm2 : Wh2))
                               : (slot == 0 ? Wl1 : (slot == 3 ? Wm1 : Wh1));
        float sgn = (slot == 1) ? -1.f : 1.f;
        u16* dst = (layer ? Wp2 : Wp1) + slot * Hout * 128;
        int total = 128 * Hout;
        for (int i = tid; i < total; i += nthr) {
            int T = i / 2048;
            int c = (i / 512) & 3;
            int lane = (i / 8) & 63;
            int j = i & 7;
            int col = T * 16 + (lane & 15);
            int k = c * 32 + (lane >> 4) * 8 + j;
            dst[i] = f2bf(sgn * W[k * Hout + col]);
        }
    }
}

// ---------------- bucket scatter (own dispatch, 512 blocks; R13's measured-best form) ------
__global__ void k_bscatter_f(const int* __restrict__ erow, const int* __restrict__ ecol, int e,
                             int nbuck, int* __restrict__ gcursor, u32* __restrict__ bedge) {
    __shared__ int hist[MAXBUCK];
    __shared__ int base[MAXBUCK];
    for (int t = threadIdx.x; t < nbuck; t += blockDim.x) hist[t] = 0;
    __syncthreads();
    int chunk = (e + gridDim.x - 1) / gridDim.x;
    int lo = blockIdx.x * chunk, hi = min(e, lo + chunk);
    for (int i = lo + threadIdx.x; i < hi; i += blockDim.x)
        atomicAdd(&hist[erow[i] >> BSHIFT], 1);
    __syncthreads();
    for (int t = threadIdx.x; t < nbuck; t += blockDim.x) {
        int c = hist[t];
        base[t] = c ? atomicAdd(&gcursor[t], c) : 0;
        hist[t] = 0;
    }
    __syncthreads();
    for (int i = lo + threadIdx.x; i < hi; i += blockDim.x) {
        int r = erow[i];
        int bk = r >> BSHIFT;
        int pos = base[bk] + atomicAdd(&hist[bk], 1);
        if (pos < BCAP)
            bedge[(size_t)bk * BCAP + pos] = ((u32)ecol[i] << 8) | (u32)(r & 255);
    }
}

// ---------------- per-bucket CSR fill with INLINE prefix scan (R15's validated k_bfill3) ----
__global__ void k_bfill3(const u32* __restrict__ bedge, const int* __restrict__ bcnt,
                         int n, int nbuck,
                         int* __restrict__ row_ptr, float* __restrict__ inv_deg,
                         int* __restrict__ cols) {
    __shared__ int cnt[256];
    __shared__ int incl[256];
    __shared__ int pos[256];
    __shared__ int lobase;
    int b = blockIdx.x, t = threadIdx.x;
    // inline exclusive prefix of bucket counts
    {
        int s = 0;
        for (int i = t; i < b; i += 256) s += bcnt[i];
        cnt[t] = s;
        __syncthreads();
        for (int off = 128; off > 0; off >>= 1) {
            if (t < off) cnt[t] += cnt[t + off];
            __syncthreads();
        }
        if (t == 0) lobase = cnt[0];
        __syncthreads();
    }
    int lo = lobase;
    int cb = bcnt[b];
    cnt[t] = 0;
    __syncthreads();
    int rbase = b << BSHIFT;
    const u32* src = bedge + (size_t)b * BCAP;
    for (int i = t; i < cb; i += 256)
        atomicAdd(&cnt[src[i] & 255u], 1);
    __syncthreads();
    int v = cnt[t];
    incl[t] = v;
    __syncthreads();
    for (int off = 1; off < 256; off <<= 1) {
        int x = (t >= off) ? incl[t - off] : 0;
        __syncthreads();
        incl[t] += x;
        __syncthreads();
    }
    int excl = incl[t] - v;
    pos[t] = excl;
    int row = rbase + t;
    if (row < n) {
        row_ptr[row] = lo + excl;
        inv_deg[row] = v > 0 ? 1.f / (float)v : 0.f;
    }
    if (b == nbuck - 1 && t == 0) row_ptr[n] = lo + cb;
    __syncthreads();
    for (int i = t; i < cb; i += 256) {
        u32 vv = src[i];
        int rl = (int)(vv & 255u);
        int p = lo + atomicAdd(&pos[rl], 1);
        cols[p] = (int)(vv >> 8);
    }
}

// ---------------- fused SpMM + GEMM + attention combine (R23 body, unchanged) ----------------
// Masked full-8 gather batches with a zero dummy row at index n. Non-persistent.
// L1 -> MT=2 (32-row tiles), L2 -> MT=1 (16-row tiles).
template<int HOUT, int MT, bool L1>
__global__ __launch_bounds__(256, 4)
void k_fused(const u32* __restrict__ X2, const int* __restrict__ row_ptr,
             const int* __restrict__ cols, const float* __restrict__ inv_deg,
             const u16* __restrict__ Wp,
             const float* __restrict__ vl, const float* __restrict__ vh, const float* __restrict__ vm,
             const float* __restrict__ att, int n,
             u16* __restrict__ feaOut, float* __restrict__ fOut) {
    constexpr int KPG = HOUT / 64;    // col-tiles per wave: 2 (L1) or 1 (L2)
    constexpr int NTw = 3 * KPG;
    constexpr int ROWS = MT * 16;
    __shared__ __align__(16) u32 AsU[MT * 1024];   // S-fragments (MT x 4c x 256 u32, swizzled)
    __shared__ __align__(16) u32 AxU[MT * 1024];   // X-fragments
    __shared__ int rctr;
    int w = threadIdx.x >> 6, lane = threadIdx.x & 63;
    int ql = lane & 15;
    int ln15 = lane & 15, lq = lane >> 4;
    int tile = xcd_swz(blockIdx.x, gridDim.x);
    int m0 = tile * ROWS;
    const u32x4* X16 = (const u32x4*)X2;   // lane ql covers u32 cols {4ql..4ql+3} = 8 bf16

    if (threadIdx.x == 0) rctr = 0;
    __syncthreads();

    // ---- gather phase: 16 quarters dynamically grab rows 0..ROWS-1 of the tile ----
    for (;;) {
        int rv;
        if (ql == 0) rv = atomicAdd(&rctr, 1);
        rv = __shfl(rv, 0, 16);
        if (rv >= ROWS) break;
        int row = m0 + rv;
        int beg = 0, end = 0;
        float s = 0.f;
        u32x4 px = {0u, 0u, 0u, 0u};
        if (row < n) {
            beg = row_ptr[row];
            end = row_ptr[row + 1];
            s = inv_deg[row];
            px = X16[(size_t)row * 16 + ql];
        }
        float a0 = 0.f, a1 = 0.f, a2 = 0.f, a3 = 0.f, a4 = 0.f, a5 = 0.f, a6 = 0.f, a7 = 0.f;
        int myc = (beg + ql < end) ? cols[beg + ql] : n;
        for (int j0 = beg; j0 < end; j0 += 16) {
            int cnt = end - j0; if (cnt > 16) cnt = 16;
            int nmy = (j0 + 16 + ql < end) ? cols[j0 + 16 + ql] : n;  // prefetch next group
            for (int j = 0; j < cnt; j += 8) {
                // masked full-8 batch: inactive lanes read the zero dummy row n
                int c0 = (j + 0 < cnt) ? __shfl(myc, j + 0, 16) : n;
                int c1 = (j + 1 < cnt) ? __shfl(myc, j + 1, 16) : n;
                int c2 = (j + 2 < cnt) ? __shfl(myc, j + 2, 16) : n;
                int c3 = (j + 3 < cnt) ? __shfl(myc, j + 3, 16) : n;
                int c4 = (j + 4 < cnt) ? __shfl(myc, j + 4, 16) : n;
                int c5 = (j + 5 < cnt) ? __shfl(myc, j + 5, 16) : n;
                int c6 = (j + 6 < cnt) ? __shfl(myc, j + 6, 16) : n;
                int c7 = (j + 7 < cnt) ? __shfl(myc, j + 7, 16) : n;
                u32x4 p0 = X16[(size_t)c0 * 16 + ql];
                u32x4 p1 = X16[(size_t)c1 * 16 + ql];
                u32x4 p2 = X16[(size_t)c2 * 16 + ql];
                u32x4 p3 = X16[(size_t)c3 * 16 + ql];
                u32x4 p4 = X16[(size_t)c4 * 16 + ql];
                u32x4 p5 = X16[(size_t)c5 * 16 + ql];
                u32x4 p6 = X16[(size_t)c6 * 16 + ql];
                u32x4 p7 = X16[(size_t)c7 * 16 + ql];
                a0 += bf2f(p0[0] & 0xffffu) + bf2f(p1[0] & 0xffffu) + bf2f(p2[0] & 0xffffu) + bf2f(p3[0] & 0xffffu)
                    + bf2f(p4[0] & 0xffffu) + bf2f(p5[0] & 0xffffu) + bf2f(p6[0] & 0xffffu) + bf2f(p7[0] & 0xffffu);
                a1 += bf2fh(p0[0]) + bf2fh(p1[0]) + bf2fh(p2[0]) + bf2fh(p3[0])
                    + bf2fh(p4[0]) + bf2fh(p5[0]) + bf2fh(p6[0]) + bf2fh(p7[0]);
                a2 += bf2f(p0[1] & 0xffffu) + bf2f(p1[1] & 0xffffu) + bf2f(p2[1] & 0xffffu) + bf2f(p3[1] & 0xffffu)
                    + bf2f(p4[1] & 0xffffu) + bf2f(p5[1] & 0xffffu) + bf2f(p6[1] & 0xffffu) + bf2f(p7[1] & 0xffffu);
                a3 += bf2fh(p0[1]) + bf2fh(p1[1]) + bf2fh(p2[1]) + bf2fh(p3[1])
                    + bf2fh(p4[1]) + bf2fh(p5[1]) + bf2fh(p6[1]) + bf2fh(p7[1]);
                a4 += bf2f(p0[2] & 0xffffu) + bf2f(p1[2] & 0xffffu) + bf2f(p2[2] & 0xffffu) + bf2f(p3[2] & 0xffffu)
                    + bf2f(p4[2] & 0xffffu) + bf2f(p5[2] & 0xffffu) + bf2f(p6[2] & 0xffffu) + bf2f(p7[2] & 0xffffu);
                a5 += bf2fh(p0[2]) + bf2fh(p1[2]) + bf2fh(p2[2]) + bf2fh(p3[2])
                    + bf2fh(p4[2]) + bf2fh(p5[2]) + bf2fh(p6[2]) + bf2fh(p7[2]);
                a6 += bf2f(p0[3] & 0xffffu) + bf2f(p1[3] & 0xffffu) + bf2f(p2[3] & 0xffffu) + bf2f(p3[3] & 0xffffu)
                    + bf2f(p4[3] & 0xffffu) + bf2f(p5[3] & 0xffffu) + bf2f(p6[3] & 0xffffu) + bf2f(p7[3] & 0xffffu);
                a7 += bf2fh(p0[3]) + bf2fh(p1[3]) + bf2fh(p2[3]) + bf2fh(p3[3])
                    + bf2fh(p4[3]) + bf2fh(p5[3]) + bf2fh(p6[3]) + bf2fh(p7[3]);
            }
            myc = nmy;
        }
        // 16B fragment chunk for local row rv: ci = rt*256 + cc*64 + qq*16 + rr (swizzled)
        int rr = rv & 15, rt = rv >> 4;
        int ci = rt * 256 + (ql >> 2) * 64 + (ql & 3) * 16 + rr;
        int d = swz(ci) * 4;
        u32x4 sv;
        sv[0] = (u32)f2bf(a0 * s) | ((u32)f2bf(a1 * s) << 16);
        sv[1] = (u32)f2bf(a2 * s) | ((u32)f2bf(a3 * s) << 16);
        sv[2] = (u32)f2bf(a4 * s) | ((u32)f2bf(a5 * s) << 16);
        sv[3] = (u32)f2bf(a6 * s) | ((u32)f2bf(a7 * s) << 16);
        *(u32x4*)(AsU + d) = sv;
        *(u32x4*)(AxU + d) = px;
    }

    f32x4 acc[MT][NTw];
#pragma unroll
    for (int mt = 0; mt < MT; ++mt)
#pragma unroll
        for (int k = 0; k < NTw; ++k) { f32x4 z = {0.f, 0.f, 0.f, 0.f}; acc[mt][k] = z; }

    __syncthreads();

    const u16* As = (const u16*)AsU;
    const u16* Ax = (const u16*)AxU;
#pragma unroll
    for (int c = 0; c < 4; ++c) {
#pragma unroll
        for (int kk = 0; kk < KPG; ++kk) {
            int T = w + kk * 4;
            size_t fo = (size_t)(T * 4 + c) * 512 + lane * 8;
            short8 bl  = *(const short8*)(Wp + (size_t)0 * (HOUT * 128) + fo);
            short8 bhn = *(const short8*)(Wp + (size_t)1 * (HOUT * 128) + fo);
            short8 bhp = *(const short8*)(Wp + (size_t)2 * (HOUT * 128) + fo);
            short8 bm  = *(const short8*)(Wp + (size_t)3 * (HOUT * 128) + fo);
#pragma unroll
            for (int mt = 0; mt < MT; ++mt) {
                int ci = (mt * 4 + c) * 64 + lane;
                int o = swz(ci) * 8;
                short8 as = *(const short8*)(As + o);
                short8 ax = *(const short8*)(Ax + o);
                acc[mt][0 * KPG + kk] = __builtin_amdgcn_mfma_f32_16x16x32_bf16(as, bl,  acc[mt][0 * KPG + kk], 0, 0, 0);
                acc[mt][1 * KPG + kk] = __builtin_amdgcn_mfma_f32_16x16x32_bf16(as, bhn, acc[mt][1 * KPG + kk], 0, 0, 0);
                acc[mt][1 * KPG + kk] = __builtin_amdgcn_mfma_f32_16x16x32_bf16(ax, bhp, acc[mt][1 * KPG + kk], 0, 0, 0);
                acc[mt][2 * KPG + kk] = __builtin_amdgcn_mfma_f32_16x16x32_bf16(ax, bm,  acc[mt][2 * KPG + kk], 0, 0, 0);
            }
        }
    }

    float vval[NTw];
#pragma unroll
    for (int k = 0; k < NTw; ++k) {
        int g = k / KPG, kk = k % KPG;
        int col = w * 16 + kk * 64 + ln15;
        vval[k] = (g == 0 ? vl : (g == 1 ? vh : vm))[col];
    }

    __shared__ float part[4][3][ROWS];
    __shared__ float wgt[ROWS][3];
#pragma unroll
    for (int mt = 0; mt < MT; ++mt) {
        float pdg[3][4];
#pragma unroll
        for (int g = 0; g < 3; ++g)
#pragma unroll
            for (int r = 0; r < 4; ++r) pdg[g][r] = 0.f;
#pragma unroll
        for (int k = 0; k < NTw; ++k) {
            int g = k / KPG;
#pragma unroll
            for (int r = 0; r < 4; ++r)
                pdg[g][r] += fmaxf(acc[mt][k][r], 0.f) * vval[k];
        }
#pragma unroll
        for (int off = 1; off < 16; off <<= 1)
#pragma unroll
            for (int g = 0; g < 3; ++g)
#pragma unroll
                for (int r = 0; r < 4; ++r)
                    pdg[g][r] += __shfl_xor(pdg[g][r], off);
        if (ln15 == 0) {
            int rbase = mt * 16 + lq * 4;
#pragma unroll
            for (int g = 0; g < 3; ++g)
#pragma unroll
                for (int r = 0; r < 4; ++r)
                    part[w][g][rbase + r] = pdg[g][r];
        }
    }
    __syncthreads();
    if (threadIdx.x < ROWS) {
        int row = threadIdx.x;
        float d0 = 0.f, d1 = 0.f, d2 = 0.f;
#pragma unroll
        for (int q = 0; q < 4; ++q) {
            d0 += part[q][0][row];
            d1 += part[q][1][row];
            d2 += part[q][2][row];
        }
        float s0 = 1.f / (1.f + __expf(-d0));
        float s1 = 1.f / (1.f + __expf(-d1));
        float s2 = 1.f / (1.f + __expf(-d2));
        float a0 = (s0 * att[0] + s1 * att[3] + s2 * att[6]) * (1.f / 3.f);
        float a1 = (s0 * att[1] + s1 * att[4] + s2 * att[7]) * (1.f / 3.f);
        float a2 = (s0 * att[2] + s1 * att[5] + s2 * att[8]) * (1.f / 3.f);
        float mx = fmaxf(a0, fmaxf(a1, a2));
        float e0 = __expf(a0 - mx), e1 = __expf(a1 - mx), e2 = __expf(a2 - mx);
        float inv = 3.f / (e0 + e1 + e2);
        wgt[row][0] = e0 * inv;
        wgt[row][1] = e1 * inv;
        wgt[row][2] = e2 * inv;
    }
    __syncthreads();

#pragma unroll
    for (int mt = 0; mt < MT; ++mt)
#pragma unroll
        for (int kk = 0; kk < KPG; ++kk)
#pragma unroll
            for (int r = 0; r < 4; ++r) {
                int row_local = mt * 16 + lq * 4 + r;
                int row = m0 + row_local;
                if (row < n) {
                    int col = w * 16 + kk * 64 + ln15;
                    float w0 = wgt[row_local][0], w1 = wgt[row_local][1], w2 = wgt[row_local][2];
                    float ol = fmaxf(acc[mt][0 * KPG + kk][r], 0.f);
                    float oh = fmaxf(acc[mt][1 * KPG + kk][r], 0.f);
                    float om = fmaxf(acc[mt][2 * KPG + kk][r], 0.f);
                    float val = w0 * ol + w1 * oh + w2 * om;
                    if (L1)
                        feaOut[(size_t)row * HOUT + col] = f2bf(fmaxf(val, 0.f));
                    else
                        fOut[(size_t)row * HOUT + col] = val;
                }
            }
}

extern "C" void kernel_launch(void* const* d_in, const int* in_sizes, int n_in,
                              void* d_out, int out_size, void* d_ws, size_t ws_size,
                              hipStream_t stream) {
    const int F = 128;
    int n = in_sizes[0] / F;
    int e = in_sizes[1] / 2;
    int nbuck = (n + (1 << BSHIFT) - 1) >> BSHIFT;
    const float* x = (const float*)d_in[0];
    const int* ei = (const int*)d_in[1];
    const int* erow = ei;
    const int* ecol = ei + e;
    const float *Wl1 = (const float*)d_in[2], *Wh1 = (const float*)d_in[3], *Wm1 = (const float*)d_in[4];
    const float *vl1 = (const float*)d_in[5], *vh1 = (const float*)d_in[6], *vm1 = (const float*)d_in[7];
    const float* att1 = (const float*)d_in[8];
    const float *Wl2 = (const float*)d_in[9], *Wh2 = (const float*)d_in[10], *Wm2 = (const float*)d_in[11];
    const float *vl2 = (const float*)d_in[12], *vh2 = (const float*)d_in[13], *vm2 = (const float*)d_in[14];
    const float* att2 = (const float*)d_in[15];
    float* out = (float*)d_out;

    char* ws = (char*)d_ws;
    size_t off = 0;
    auto alloc = [&](size_t b) -> void* {
        void* p = ws + off;
        off = (off + b + 255) & ~(size_t)255;
        return p;
    };
    int* row_ptr = (int*)alloc((size_t)(n + 1) * 4);
    float* inv_deg = (float*)alloc((size_t)n * 4);
    int* gcursor = (int*)alloc(MAXBUCK * 4);
    u32* bedge = (u32*)alloc((size_t)MAXBUCK * BCAP * 4);
    int* cols = (int*)alloc((size_t)e * 4);
    u16* Xb = (u16*)alloc((size_t)(n + 1) * 128 * 2);   // +1 zero dummy row (gather mask target)
    u16* fea = (u16*)alloc((size_t)(n + 1) * 128 * 2);  // +1 zero dummy row
    u16* Wp1 = (u16*)alloc((size_t)4 * 128 * 128 * 2);
    u16* Wp2 = (u16*)alloc((size_t)4 * 64 * 128 * 2);
    (void)ws_size; (void)n_in; (void)out_size;

    hipMemsetAsync(gcursor, 0, (size_t)MAXBUCK * 4, stream);

    k_prep<<<CASTBLK + 16, 256, 0, stream>>>((const float4*)x, (u32*)Xb, (long)n * 32,
                                             Wl1, Wh1, Wm1, Wl2, Wh2, Wm2, Wp1, Wp2,
                                             (u32*)(Xb + (size_t)n * 128),
                                             (u32*)(fea + (size_t)n * 128));
    k_bscatter_f<<<SCATBLK, 256, 0, stream>>>(erow, ecol, e, nbuck, gcursor, bedge);
    k_bfill3<<<nbuck, 256, 0, stream>>>(bedge, gcursor, n, nbuck, row_ptr, inv_deg, cols);

    int gb1 = (n + 31) / 32;
    int gb2 = (n + 15) / 16;

    // layer 1 (fused spmm+gemm, 32-row tiles)
    k_fused<128, 2, true><<<gb1, 256, 0, stream>>>((const u32*)Xb, row_ptr, cols, inv_deg,
                                                   Wp1, vl1, vh1, vm1, att1, n, fea, nullptr);
    // layer 2 (16-row tiles)
    k_fused<64, 1, false><<<gb2, 256, 0, stream>>>((const u32*)fea, row_ptr, cols, inv_deg,
                                                   Wp2, vl2, vh2, vm2, att2, n, nullptr, out);
}